// Round 14
// baseline (132.926 us; speedup 1.0000x reference)
//
#include <hip/hip_runtime.h>

#define IN_F 256
#define OUT_F 64
#define LOGSB 8           // 256 nodes per super-bucket
#define SBNODES 256
#define MAXSB 1024        // supports N <= 131072 (src must fit 17 bits)

typedef __bf16 bf16x8 __attribute__((ext_vector_type(8)));
typedef float f32x4 __attribute__((ext_vector_type(4)));

// ---------------------------------------------------------------- W fragment prep (+ zero bcnt, sbcur)
__global__ __launch_bounds__(64) void wfrag_kernel(const float* __restrict__ W,
                                                   __bf16* __restrict__ wfrag,
                                                   int* __restrict__ bcnt,
                                                   int* __restrict__ sbcur, int nsb) {
    const int st = blockIdx.x;
    const int l = threadIdx.x;
    if (st == 0)
        for (int i = l; i <= nsb; i += 64) bcnt[i] = 0;
    if (st == 1)
        for (int i = l; i < nsb; i += 64) sbcur[i] = 0;
    const int s = st >> 2, t = st & 3;
    const int n = t * 16 + (l & 15);
    const int k0 = s * 32 + (l >> 4) * 8;
    bf16x8 f;
#pragma unroll
    for (int j = 0; j < 8; ++j)
        f[j] = (__bf16)W[(k0 + j) * OUT_F + n];
    *(bf16x8*)(wfrag + (size_t)(st * 64 + l) * 8) = f;
}

// ---------------------------------------------------------------- super-bucket histogram (standalone)
__global__ __launch_bounds__(256) void sbhist_kernel(const int* __restrict__ dst,
                                                     int* __restrict__ bcnt, int E, int nsb) {
    __shared__ int histo[MAXSB];
    for (int i = threadIdx.x; i < nsb; i += 256) histo[i] = 0;
    __syncthreads();
    const int stride = gridDim.x * 1024;
    for (int base = (blockIdx.x * 256 + threadIdx.x) * 4; base < E; base += stride) {
        if (base + 4 <= E) {
            int4 d4 = *(const int4*)(dst + base);
            atomicAdd(&histo[d4.x >> LOGSB], 1);
            atomicAdd(&histo[d4.y >> LOGSB], 1);
            atomicAdd(&histo[d4.z >> LOGSB], 1);
            atomicAdd(&histo[d4.w >> LOGSB], 1);
        } else {
            for (int e = base; e < E; ++e) atomicAdd(&histo[dst[e] >> LOGSB], 1);
        }
    }
    __syncthreads();
    for (int i = threadIdx.x; i < nsb; i += 256)
        if (histo[i]) atomicAdd(&bcnt[i], histo[i]);
}

// ---------------------------------------------------------------- fused sbscatter ∥ MFMA GEMM
// Blocks [0, scatBlocks): scatter 4096 edges each into super-bucket regions
// (latency/atomic-bound). Blocks [scatBlocks, end): GEMM h = feat @ W
// (HBM-stream-bound). Complementary regimes -> co-scheduled overlap.
__global__ __launch_bounds__(256) void scatgemm_kernel(const int* __restrict__ src,
                                                       const int* __restrict__ dst,
                                                       const float* __restrict__ ew,
                                                       const int* __restrict__ bcnt,
                                                       int* __restrict__ sbcur,
                                                       int2* __restrict__ payload,
                                                       int E, int nsb,
                                                       const float* __restrict__ feat,
                                                       const __bf16* __restrict__ wfrag,
                                                       __bf16* __restrict__ h, int N,
                                                       int scatBlocks) {
    __shared__ int s[256];
    __shared__ int sbb[MAXSB];
    __shared__ int cnt[MAXSB];
    __shared__ int basearr[MAXSB];
    const int t = threadIdx.x;

    if ((int)blockIdx.x < scatBlocks) {
        // ---------------- scatter branch: 16 edges/thread, 4096/block ----------------
        // local exclusive scan of bcnt -> sbb (4 elems/thread, identical per block)
        int v[4];
        int sum = 0;
#pragma unroll
        for (int q = 0; q < 4; ++q) {
            int i = 4 * t + q;
            v[q] = (i < nsb) ? bcnt[i] : 0;
            sum += v[q];
        }
        s[t] = sum;
        __syncthreads();
        for (int o = 1; o < 256; o <<= 1) {
            int x = (t >= o) ? s[t - o] : 0;
            __syncthreads();
            s[t] += x;
            __syncthreads();
        }
        int ex = s[t] - sum;
#pragma unroll
        for (int q = 0; q < 4; ++q) {
            int i = 4 * t + q;
            if (i < nsb) sbb[i] = ex;
            ex += v[q];
        }
        for (int i = t; i < nsb; i += 256) cnt[i] = 0;
        __syncthreads();

        const int base = blockIdx.x * 4096 + t * 16;
        int dd[16], ss[16];
        float ww[16];
        int nv = 0;
        if (base + 16 <= E) {
#pragma unroll
            for (int q = 0; q < 4; ++q) {
                int4 d4 = *(const int4*)(dst + base + q * 4);
                int4 s4 = *(const int4*)(src + base + q * 4);
                float4 w4 = *(const float4*)(ew + base + q * 4);
                dd[q * 4 + 0] = d4.x; dd[q * 4 + 1] = d4.y;
                dd[q * 4 + 2] = d4.z; dd[q * 4 + 3] = d4.w;
                ss[q * 4 + 0] = s4.x; ss[q * 4 + 1] = s4.y;
                ss[q * 4 + 2] = s4.z; ss[q * 4 + 3] = s4.w;
                ww[q * 4 + 0] = w4.x; ww[q * 4 + 1] = w4.y;
                ww[q * 4 + 2] = w4.z; ww[q * 4 + 3] = w4.w;
            }
            nv = 16;
        } else if (base < E) {
            nv = E - base;
#pragma unroll 16
            for (int q = 0; q < 16; ++q)
                if (q < nv) { dd[q] = dst[base + q]; ss[q] = src[base + q]; ww[q] = ew[base + q]; }
        }

        int idx[16];
#pragma unroll 16
        for (int q = 0; q < 16; ++q)
            if (q < nv) idx[q] = atomicAdd(&cnt[dd[q] >> LOGSB], 1);
        __syncthreads();

        for (int i = t; i < nsb; i += 256)
            if (cnt[i]) basearr[i] = sbb[i] + atomicAdd(&sbcur[i], cnt[i]);
        __syncthreads();

#pragma unroll 16
        for (int q = 0; q < 16; ++q)
            if (q < nv) {
                int pos = basearr[dd[q] >> LOGSB] + idx[q];
                payload[pos] = make_int2(ss[q] | ((dd[q] & (SBNODES - 1)) << 24),
                                         __float_as_int(ww[q]));
            }
    } else {
        // ---------------- GEMM branch ----------------
        const int gb = blockIdx.x - scatBlocks;
        const int wv = t >> 6;
        const int l = t & 63;
        const int m0 = gb * 64 + wv * 16;
        const int q = l >> 4;
        const int row = min(m0 + (l & 15), N - 1);

        const float* __restrict__ arow = feat + (size_t)row * IN_F + q * 8;
        const bf16x8* __restrict__ wf = (const bf16x8*)wfrag;

        f32x4 acc0 = {0.f, 0.f, 0.f, 0.f};
        f32x4 acc1 = {0.f, 0.f, 0.f, 0.f};
        f32x4 acc2 = {0.f, 0.f, 0.f, 0.f};
        f32x4 acc3 = {0.f, 0.f, 0.f, 0.f};

#pragma unroll
        for (int sK = 0; sK < 8; ++sK) {
            float4 fa0 = *(const float4*)(arow + sK * 32);
            float4 fa1 = *(const float4*)(arow + sK * 32 + 4);
            bf16x8 a;
            a[0] = (__bf16)fa0.x; a[1] = (__bf16)fa0.y;
            a[2] = (__bf16)fa0.z; a[3] = (__bf16)fa0.w;
            a[4] = (__bf16)fa1.x; a[5] = (__bf16)fa1.y;
            a[6] = (__bf16)fa1.z; a[7] = (__bf16)fa1.w;
            bf16x8 b0 = wf[(sK * 4 + 0) * 64 + l];
            bf16x8 b1 = wf[(sK * 4 + 1) * 64 + l];
            bf16x8 b2 = wf[(sK * 4 + 2) * 64 + l];
            bf16x8 b3 = wf[(sK * 4 + 3) * 64 + l];
            acc0 = __builtin_amdgcn_mfma_f32_16x16x32_bf16(a, b0, acc0, 0, 0, 0);
            acc1 = __builtin_amdgcn_mfma_f32_16x16x32_bf16(a, b1, acc1, 0, 0, 0);
            acc2 = __builtin_amdgcn_mfma_f32_16x16x32_bf16(a, b2, acc2, 0, 0, 0);
            acc3 = __builtin_amdgcn_mfma_f32_16x16x32_bf16(a, b3, acc3, 0, 0, 0);
        }

        const int colb = l & 15;
#pragma unroll
        for (int r = 0; r < 4; ++r) {
            int ro = m0 + q * 4 + r;
            if (ro < N) {
                __bf16* hp = h + (size_t)ro * OUT_F + colb;
                hp[0]  = (__bf16)acc0[r];
                hp[16] = (__bf16)acc1[r];
                hp[32] = (__bf16)acc2[r];
                hp[48] = (__bf16)acc3[r];
            }
        }
    }
}

// ---------------------------------------------------------------- fine sort within super-bucket
// Writes PACKED payload2: (src << 15) | (bf16(w) & 0x7FFF).
__global__ __launch_bounds__(256) void fsort_kernel(const int2* __restrict__ payload,
                                                    unsigned* __restrict__ payload2,
                                                    const int* __restrict__ bcnt,
                                                    int* __restrict__ noff,
                                                    int N, int E, int nsb) {
    __shared__ int red[256];
    __shared__ int cnt[SBNODES];
    __shared__ int off[SBNODES + 1];
    __shared__ int tick[SBNODES];
    const int t = threadIdx.x;
    const int bid = blockIdx.x;

    int partial = 0;
    for (int i = t; i < bid; i += 256) partial += bcnt[i];
    red[t] = partial;
    __syncthreads();
    for (int o = 128; o > 0; o >>= 1) {
        if (t < o) red[t] += red[t + o];
        __syncthreads();
    }
    const int b = red[0];
    const int m = bcnt[bid];
    const int mlim = min(m, 4096);

    int2 ed[16];
#pragma unroll
    for (int k = 0; k < 16; ++k) {
        int i = t + k * 256;
        if (i < mlim) ed[k] = payload[b + i];
    }

    cnt[t] = 0;
    __syncthreads();
#pragma unroll
    for (int k = 0; k < 16; ++k) {
        int i = t + k * 256;
        if (i < mlim) atomicAdd(&cnt[((unsigned)ed[k].x) >> 24], 1);
    }
    for (int i = 4096 + t; i < m; i += 256)
        atomicAdd(&cnt[((unsigned)payload[b + i].x) >> 24], 1);
    __syncthreads();

    if (t == 0) off[0] = 0;
    off[t + 1] = cnt[t];
    __syncthreads();
    for (int o = 1; o < SBNODES; o <<= 1) {
        int v2 = (t >= o) ? off[t + 1 - o] : 0;
        __syncthreads();
        off[t + 1] += v2;
        __syncthreads();
    }

    const int g = (bid << LOGSB) + t;
    if (g < N) noff[g] = b + off[t];
    if (bid == 0 && t == 0) noff[N] = E;
    tick[t] = 0;
    __syncthreads();

#pragma unroll
    for (int k = 0; k < 16; ++k) {
        int i = t + k * 256;
        if (i < mlim) {
            int2 p = ed[k];
            int ld = ((unsigned)p.x) >> 24;
            int pos = b + off[ld] + atomicAdd(&tick[ld], 1);
            unsigned wb = (unsigned)p.y;
            unsigned b16 = (wb + 0x7FFFu + ((wb >> 16) & 1u)) >> 16;   // RNE f32->bf16
            payload2[pos] = (((unsigned)(p.x & 0xFFFFFF)) << 15) | (b16 & 0x7FFFu);
        }
    }
    for (int i = 4096 + t; i < m; i += 256) {
        int2 p = payload[b + i];
        int ld = ((unsigned)p.x) >> 24;
        int pos = b + off[ld] + atomicAdd(&tick[ld], 1);
        unsigned wb = (unsigned)p.y;
        unsigned b16 = (wb + 0x7FFFu + ((wb >> 16) & 1u)) >> 16;
        payload2[pos] = (((unsigned)(p.x & 0xFFFFFF)) << 15) | (b16 & 0x7FFFu);
    }
}

// ---------------------------------------------------------------- gather + ReLU (packed 4B edges)
#define EDGE8P(PBASE, A0A, A0B, A1A, A1B, A2A, A2B, A3A, A3B)                   \
    {                                                                           \
        unsigned p0 = (PBASE)[0];                                               \
        unsigned p1 = (PBASE)[1];                                               \
        unsigned p2 = (PBASE)[2];                                               \
        unsigned p3 = (PBASE)[3];                                               \
        unsigned p4 = (PBASE)[4];                                               \
        unsigned p5 = (PBASE)[5];                                               \
        unsigned p6 = (PBASE)[6];                                               \
        unsigned p7 = (PBASE)[7];                                               \
        unsigned v0 = h32[(size_t)(p0 >> 15) * 32 + j];                         \
        unsigned v1 = h32[(size_t)(p1 >> 15) * 32 + j];                         \
        unsigned v2 = h32[(size_t)(p2 >> 15) * 32 + j];                         \
        unsigned v3 = h32[(size_t)(p3 >> 15) * 32 + j];                         \
        unsigned v4 = h32[(size_t)(p4 >> 15) * 32 + j];                         \
        unsigned v5 = h32[(size_t)(p5 >> 15) * 32 + j];                         \
        unsigned v6 = h32[(size_t)(p6 >> 15) * 32 + j];                         \
        unsigned v7 = h32[(size_t)(p7 >> 15) * 32 + j];                         \
        float w0 = __uint_as_float((p0 & 0x7FFFu) << 16);                       \
        float w1 = __uint_as_float((p1 & 0x7FFFu) << 16);                       \
        float w2 = __uint_as_float((p2 & 0x7FFFu) << 16);                       \
        float w3 = __uint_as_float((p3 & 0x7FFFu) << 16);                       \
        float w4 = __uint_as_float((p4 & 0x7FFFu) << 16);                       \
        float w5 = __uint_as_float((p5 & 0x7FFFu) << 16);                       \
        float w6 = __uint_as_float((p6 & 0x7FFFu) << 16);                       \
        float w7 = __uint_as_float((p7 & 0x7FFFu) << 16);                       \
        A0A = fmaf(__uint_as_float(v0 << 16), w0, A0A);                         \
        A0B = fmaf(__uint_as_float(v0 & 0xFFFF0000u), w0, A0B);                 \
        A1A = fmaf(__uint_as_float(v1 << 16), w1, A1A);                         \
        A1B = fmaf(__uint_as_float(v1 & 0xFFFF0000u), w1, A1B);                 \
        A2A = fmaf(__uint_as_float(v2 << 16), w2, A2A);                         \
        A2B = fmaf(__uint_as_float(v2 & 0xFFFF0000u), w2, A2B);                 \
        A3A = fmaf(__uint_as_float(v3 << 16), w3, A3A);                         \
        A3B = fmaf(__uint_as_float(v3 & 0xFFFF0000u), w3, A3B);                 \
        A0A = fmaf(__uint_as_float(v4 << 16), w4, A0A);                         \
        A0B = fmaf(__uint_as_float(v4 & 0xFFFF0000u), w4, A0B);                 \
        A1A = fmaf(__uint_as_float(v5 << 16), w5, A1A);                         \
        A1B = fmaf(__uint_as_float(v5 & 0xFFFF0000u), w5, A1B);                 \
        A2A = fmaf(__uint_as_float(v6 << 16), w6, A2A);                         \
        A2B = fmaf(__uint_as_float(v6 & 0xFFFF0000u), w6, A2B);                 \
        A3A = fmaf(__uint_as_float(v7 << 16), w7, A3A);                         \
        A3B = fmaf(__uint_as_float(v7 & 0xFFFF0000u), w7, A3B);                 \
    }

__global__ __launch_bounds__(256) void bgather_kernel(const __bf16* __restrict__ h,
                                                      const unsigned* __restrict__ payload2,
                                                      const int* __restrict__ noff,
                                                      float* __restrict__ out, int N) {
    const int t = threadIdx.x;
    const int hw = t >> 5;
    const int j = t & 31;
    const unsigned* __restrict__ h32 = (const unsigned*)h;
    const int g0 = blockIdx.x * 32;

#pragma unroll 1
    for (int k = 0; k < 4; ++k) {
        const int g = g0 + hw + k * 8;
        if (g >= N) continue;
        int i = noff[g];
        const int eE = noff[g + 1];
        float a0A = 0.f, a0B = 0.f, a1A = 0.f, a1B = 0.f;
        float a2A = 0.f, a2B = 0.f, a3A = 0.f, a3B = 0.f;
        float b0A = 0.f, b0B = 0.f, b1A = 0.f, b1B = 0.f;
        float b2A = 0.f, b2B = 0.f, b3A = 0.f, b3B = 0.f;
#pragma unroll 1
        for (; i + 16 <= eE; i += 16) {
            EDGE8P(payload2 + i, a0A, a0B, a1A, a1B, a2A, a2B, a3A, a3B)
            EDGE8P(payload2 + i + 8, b0A, b0B, b1A, b1B, b2A, b2B, b3A, b3B)
        }
        if (i + 8 <= eE) {
            EDGE8P(payload2 + i, a0A, a0B, a1A, a1B, a2A, a2B, a3A, a3B)
            i += 8;
        }
        for (; i + 2 <= eE; i += 2) {
            unsigned p0 = payload2[i + 0];
            unsigned p1 = payload2[i + 1];
            unsigned v0 = h32[(size_t)(p0 >> 15) * 32 + j];
            unsigned v1 = h32[(size_t)(p1 >> 15) * 32 + j];
            float w0 = __uint_as_float((p0 & 0x7FFFu) << 16);
            float w1 = __uint_as_float((p1 & 0x7FFFu) << 16);
            a0A = fmaf(__uint_as_float(v0 << 16), w0, a0A);
            a0B = fmaf(__uint_as_float(v0 & 0xFFFF0000u), w0, a0B);
            a1A = fmaf(__uint_as_float(v1 << 16), w1, a1A);
            a1B = fmaf(__uint_as_float(v1 & 0xFFFF0000u), w1, a1B);
        }
        if (i < eE) {
            unsigned p0 = payload2[i];
            unsigned v0 = h32[(size_t)(p0 >> 15) * 32 + j];
            float w0 = __uint_as_float((p0 & 0x7FFFu) << 16);
            a0A = fmaf(__uint_as_float(v0 << 16), w0, a0A);
            a0B = fmaf(__uint_as_float(v0 & 0xFFFF0000u), w0, a0B);
        }
        float2 v;
        v.x = fmaxf(((a0A + a1A) + (a2A + a3A)) + ((b0A + b1A) + (b2A + b3A)), 0.f);
        v.y = fmaxf(((a0B + a1B) + (a2B + a3B)) + ((b0B + b1B) + (b2B + b3B)), 0.f);
        *(float2*)(out + (size_t)g * OUT_F + 2 * j) = v;
    }
}

// ---------------------------------------------------------------- launch
extern "C" void kernel_launch(void* const* d_in, const int* in_sizes, int n_in,
                              void* d_out, int out_size, void* d_ws, size_t ws_size,
                              hipStream_t stream) {
    const float* feat = (const float*)d_in[0];
    const float* W    = (const float*)d_in[1];
    const float* ew   = (const float*)d_in[2];
    const int*   src  = (const int*)d_in[3];
    const int*   dst  = (const int*)d_in[4];
    float* out = (float*)d_out;

    const int N = in_sizes[0] / IN_F;
    const int E = in_sizes[2];
    const int nsb = (N + SBNODES - 1) >> LOGSB;

    char* ws = (char*)d_ws;
    int2*     payload  = (int2*)ws;     ws += (size_t)E * 8;          // 12.8 MB
    unsigned* payload2 = (unsigned*)ws; ws += (size_t)E * 4;          //  6.4 MB
    __bf16*   h        = (__bf16*)ws;   ws += (size_t)N * OUT_F * 2;  // 12.8 MB
    __bf16*   wfrag    = (__bf16*)ws;   ws += 32 * 64 * 8 * 2;        // 32 KB
    int*      bcnt     = (int*)ws;      ws += (MAXSB + 1) * 4;
    int*      sbcur    = (int*)ws;      ws += MAXSB * 4;
    int*      noff     = (int*)ws;                                    // (N+1)*4

    const int gemmBlocks = (N + 63) / 64;
    const int scatBlocks = (E + 4095) / 4096;

    hipLaunchKernelGGL(wfrag_kernel, dim3(32), dim3(64), 0, stream, W, wfrag, bcnt, sbcur, nsb);
    hipLaunchKernelGGL(sbhist_kernel, dim3(512), dim3(256), 0, stream, dst, bcnt, E, nsb);
    hipLaunchKernelGGL(scatgemm_kernel, dim3(scatBlocks + gemmBlocks), dim3(256), 0, stream,
                       src, dst, ew, bcnt, sbcur, payload, E, nsb,
                       feat, wfrag, h, N, scatBlocks);
    hipLaunchKernelGGL(fsort_kernel, dim3(nsb), dim3(256), 0, stream,
                       payload, payload2, bcnt, noff, N, E, nsb);
    hipLaunchKernelGGL(bgather_kernel, dim3((N + 31) / 32), dim3(256), 0, stream,
                       h, payload2, noff, out, N);
}

// Round 15
// 117.925 us; speedup vs baseline: 1.1272x; 1.1272x over previous
//
#include <hip/hip_runtime.h>

#define IN_F 256
#define OUT_F 64
#define LOGSB 8           // 256 nodes per super-bucket
#define SBNODES 256
#define MAXSB 1024        // supports N <= 131072 (src must fit 17 bits)

typedef __bf16 bf16x8 __attribute__((ext_vector_type(8)));
typedef float f32x4 __attribute__((ext_vector_type(4)));

// ---------------------------------------------------------------- W fragment prep (+ zero bcnt, sbcur)
__global__ __launch_bounds__(64) void wfrag_kernel(const float* __restrict__ W,
                                                   __bf16* __restrict__ wfrag,
                                                   int* __restrict__ bcnt,
                                                   int* __restrict__ sbcur, int nsb) {
    const int st = blockIdx.x;
    const int l = threadIdx.x;
    if (st == 0)
        for (int i = l; i <= nsb; i += 64) bcnt[i] = 0;
    if (st == 1)
        for (int i = l; i < nsb; i += 64) sbcur[i] = 0;
    const int s = st >> 2, t = st & 3;
    const int n = t * 16 + (l & 15);
    const int k0 = s * 32 + (l >> 4) * 8;
    bf16x8 f;
#pragma unroll
    for (int j = 0; j < 8; ++j)
        f[j] = (__bf16)W[(k0 + j) * OUT_F + n];
    *(bf16x8*)(wfrag + (size_t)(st * 64 + l) * 8) = f;
}

// ---------------------------------------------------------------- fused MFMA GEMM + super-bucket histogram
__global__ __launch_bounds__(256) void gemmhist_kernel(const float* __restrict__ feat,
                                                       const __bf16* __restrict__ wfrag,
                                                       __bf16* __restrict__ h, int N,
                                                       const int* __restrict__ dst,
                                                       int* __restrict__ bcnt, int E, int nsb,
                                                       int gemmBlocks) {
    __shared__ int histo[MAXSB];
    if ((int)blockIdx.x < gemmBlocks) {
        const int tid = threadIdx.x;
        const int wv = tid >> 6;
        const int l = tid & 63;
        const int m0 = blockIdx.x * 64 + wv * 16;
        const int q = l >> 4;
        const int row = min(m0 + (l & 15), N - 1);

        const float* __restrict__ arow = feat + (size_t)row * IN_F + q * 8;
        const bf16x8* __restrict__ wf = (const bf16x8*)wfrag;

        f32x4 acc0 = {0.f, 0.f, 0.f, 0.f};
        f32x4 acc1 = {0.f, 0.f, 0.f, 0.f};
        f32x4 acc2 = {0.f, 0.f, 0.f, 0.f};
        f32x4 acc3 = {0.f, 0.f, 0.f, 0.f};

#pragma unroll
        for (int s = 0; s < 8; ++s) {
            float4 fa0 = *(const float4*)(arow + s * 32);
            float4 fa1 = *(const float4*)(arow + s * 32 + 4);
            bf16x8 a;
            a[0] = (__bf16)fa0.x; a[1] = (__bf16)fa0.y;
            a[2] = (__bf16)fa0.z; a[3] = (__bf16)fa0.w;
            a[4] = (__bf16)fa1.x; a[5] = (__bf16)fa1.y;
            a[6] = (__bf16)fa1.z; a[7] = (__bf16)fa1.w;
            bf16x8 b0 = wf[(s * 4 + 0) * 64 + l];
            bf16x8 b1 = wf[(s * 4 + 1) * 64 + l];
            bf16x8 b2 = wf[(s * 4 + 2) * 64 + l];
            bf16x8 b3 = wf[(s * 4 + 3) * 64 + l];
            acc0 = __builtin_amdgcn_mfma_f32_16x16x32_bf16(a, b0, acc0, 0, 0, 0);
            acc1 = __builtin_amdgcn_mfma_f32_16x16x32_bf16(a, b1, acc1, 0, 0, 0);
            acc2 = __builtin_amdgcn_mfma_f32_16x16x32_bf16(a, b2, acc2, 0, 0, 0);
            acc3 = __builtin_amdgcn_mfma_f32_16x16x32_bf16(a, b3, acc3, 0, 0, 0);
        }

        const int colb = l & 15;
#pragma unroll
        for (int r = 0; r < 4; ++r) {
            int ro = m0 + q * 4 + r;
            if (ro < N) {
                __bf16* hp = h + (size_t)ro * OUT_F + colb;
                hp[0]  = (__bf16)acc0[r];
                hp[16] = (__bf16)acc1[r];
                hp[32] = (__bf16)acc2[r];
                hp[48] = (__bf16)acc3[r];
            }
        }
    } else {
        const int hb = blockIdx.x - gemmBlocks;
        const int nhb = gridDim.x - gemmBlocks;
        for (int i = threadIdx.x; i < nsb; i += 256) histo[i] = 0;
        __syncthreads();
        const int stride = nhb * 1024;
        for (int base = (hb * 256 + threadIdx.x) * 4; base < E; base += stride) {
            if (base + 4 <= E) {
                int4 d4 = *(const int4*)(dst + base);
                atomicAdd(&histo[d4.x >> LOGSB], 1);
                atomicAdd(&histo[d4.y >> LOGSB], 1);
                atomicAdd(&histo[d4.z >> LOGSB], 1);
                atomicAdd(&histo[d4.w >> LOGSB], 1);
            } else {
                for (int e = base; e < E; ++e) atomicAdd(&histo[dst[e] >> LOGSB], 1);
            }
        }
        __syncthreads();
        for (int i = threadIdx.x; i < nsb; i += 256)
            if (histo[i]) atomicAdd(&bcnt[i], histo[i]);
    }
}

// ---------------------------------------------------------------- super-bucket scatter (local scan, 8 edges/thread)
__global__ __launch_bounds__(1024) void sbscatter_kernel(const int* __restrict__ src,
                                                         const int* __restrict__ dst,
                                                         const float* __restrict__ ew,
                                                         const int* __restrict__ bcnt,
                                                         int* __restrict__ sbcur,
                                                         int2* __restrict__ payload,
                                                         int E, int nsb) {
    __shared__ int s[1024];
    __shared__ int sbb[MAXSB];
    __shared__ int cnt[MAXSB];
    __shared__ int basearr[MAXSB];
    const int t = threadIdx.x;

    // local exclusive scan of bcnt -> sbb (identical in every block)
    int v = (t < nsb) ? bcnt[t] : 0;
    s[t] = v;
    __syncthreads();
    for (int o = 1; o < 1024; o <<= 1) {
        int x = (t >= o) ? s[t - o] : 0;
        __syncthreads();
        s[t] += x;
        __syncthreads();
    }
    if (t < nsb) sbb[t] = s[t] - v;
    for (int i = t; i < nsb; i += 1024) cnt[i] = 0;
    __syncthreads();

    const int base = (blockIdx.x * 1024 + t) * 8;
    int dd[8], ss[8];
    float ww[8];
    int nv = 0;
    if (base + 8 <= E) {
        int4 d4a = *(const int4*)(dst + base);
        int4 d4b = *(const int4*)(dst + base + 4);
        int4 s4a = *(const int4*)(src + base);
        int4 s4b = *(const int4*)(src + base + 4);
        float4 w4a = *(const float4*)(ew + base);
        float4 w4b = *(const float4*)(ew + base + 4);
        dd[0] = d4a.x; dd[1] = d4a.y; dd[2] = d4a.z; dd[3] = d4a.w;
        dd[4] = d4b.x; dd[5] = d4b.y; dd[6] = d4b.z; dd[7] = d4b.w;
        ss[0] = s4a.x; ss[1] = s4a.y; ss[2] = s4a.z; ss[3] = s4a.w;
        ss[4] = s4b.x; ss[5] = s4b.y; ss[6] = s4b.z; ss[7] = s4b.w;
        ww[0] = w4a.x; ww[1] = w4a.y; ww[2] = w4a.z; ww[3] = w4a.w;
        ww[4] = w4b.x; ww[5] = w4b.y; ww[6] = w4b.z; ww[7] = w4b.w;
        nv = 8;
    } else if (base < E) {
        nv = E - base;
#pragma unroll 8
        for (int j = 0; j < 8; ++j)
            if (j < nv) { dd[j] = dst[base + j]; ss[j] = src[base + j]; ww[j] = ew[base + j]; }
    }

    int idx[8];
#pragma unroll 8
    for (int j = 0; j < 8; ++j)
        if (j < nv) idx[j] = atomicAdd(&cnt[dd[j] >> LOGSB], 1);
    __syncthreads();

    for (int i = t; i < nsb; i += 1024)
        if (cnt[i]) basearr[i] = sbb[i] + atomicAdd(&sbcur[i], cnt[i]);
    __syncthreads();

#pragma unroll 8
    for (int j = 0; j < 8; ++j)
        if (j < nv) {
            int pos = basearr[dd[j] >> LOGSB] + idx[j];
            payload[pos] = make_int2(ss[j] | ((dd[j] & (SBNODES - 1)) << 24),
                                     __float_as_int(ww[j]));
        }
}

// ---------------------------------------------------------------- fine sort within super-bucket
// Writes PACKED payload2: (src << 15) | (bf16(w) & 0x7FFF). w >= 0 so the sign
// bit is free; src < 2^17. RNE f32->bf16.
__global__ __launch_bounds__(256) void fsort_kernel(const int2* __restrict__ payload,
                                                    unsigned* __restrict__ payload2,
                                                    const int* __restrict__ bcnt,
                                                    int* __restrict__ noff,
                                                    int N, int E, int nsb) {
    __shared__ int red[256];
    __shared__ int cnt[SBNODES];
    __shared__ int off[SBNODES + 1];
    __shared__ int tick[SBNODES];
    const int t = threadIdx.x;
    const int bid = blockIdx.x;

    int partial = 0;
    for (int i = t; i < bid; i += 256) partial += bcnt[i];
    red[t] = partial;
    __syncthreads();
    for (int o = 128; o > 0; o >>= 1) {
        if (t < o) red[t] += red[t + o];
        __syncthreads();
    }
    const int b = red[0];
    const int m = bcnt[bid];
    const int mlim = min(m, 4096);

    int2 ed[16];
#pragma unroll
    for (int k = 0; k < 16; ++k) {
        int i = t + k * 256;
        if (i < mlim) ed[k] = payload[b + i];
    }

    cnt[t] = 0;
    __syncthreads();
#pragma unroll
    for (int k = 0; k < 16; ++k) {
        int i = t + k * 256;
        if (i < mlim) atomicAdd(&cnt[((unsigned)ed[k].x) >> 24], 1);
    }
    for (int i = 4096 + t; i < m; i += 256)
        atomicAdd(&cnt[((unsigned)payload[b + i].x) >> 24], 1);
    __syncthreads();

    if (t == 0) off[0] = 0;
    off[t + 1] = cnt[t];
    __syncthreads();
    for (int o = 1; o < SBNODES; o <<= 1) {
        int v2 = (t >= o) ? off[t + 1 - o] : 0;
        __syncthreads();
        off[t + 1] += v2;
        __syncthreads();
    }

    const int g = (bid << LOGSB) + t;
    if (g < N) noff[g] = b + off[t];
    if (bid == 0 && t == 0) noff[N] = E;
    tick[t] = 0;
    __syncthreads();

#pragma unroll
    for (int k = 0; k < 16; ++k) {
        int i = t + k * 256;
        if (i < mlim) {
            int2 p = ed[k];
            int ld = ((unsigned)p.x) >> 24;
            int pos = b + off[ld] + atomicAdd(&tick[ld], 1);
            unsigned wb = (unsigned)p.y;
            unsigned b16 = (wb + 0x7FFFu + ((wb >> 16) & 1u)) >> 16;   // RNE f32->bf16
            payload2[pos] = (((unsigned)(p.x & 0xFFFFFF)) << 15) | (b16 & 0x7FFFu);
        }
    }
    for (int i = 4096 + t; i < m; i += 256) {
        int2 p = payload[b + i];
        int ld = ((unsigned)p.x) >> 24;
        int pos = b + off[ld] + atomicAdd(&tick[ld], 1);
        unsigned wb = (unsigned)p.y;
        unsigned b16 = (wb + 0x7FFFu + ((wb >> 16) & 1u)) >> 16;
        payload2[pos] = (((unsigned)(p.x & 0xFFFFFF)) << 15) | (b16 & 0x7FFFu);
    }
}

// ---------------------------------------------------------------- gather + ReLU (packed 4B edges)
#define EDGE8P(PBASE, A0A, A0B, A1A, A1B, A2A, A2B, A3A, A3B)                   \
    {                                                                           \
        unsigned p0 = (PBASE)[0];                                               \
        unsigned p1 = (PBASE)[1];                                               \
        unsigned p2 = (PBASE)[2];                                               \
        unsigned p3 = (PBASE)[3];                                               \
        unsigned p4 = (PBASE)[4];                                               \
        unsigned p5 = (PBASE)[5];                                               \
        unsigned p6 = (PBASE)[6];                                               \
        unsigned p7 = (PBASE)[7];                                               \
        unsigned v0 = h32[(size_t)(p0 >> 15) * 32 + j];                         \
        unsigned v1 = h32[(size_t)(p1 >> 15) * 32 + j];                         \
        unsigned v2 = h32[(size_t)(p2 >> 15) * 32 + j];                         \
        unsigned v3 = h32[(size_t)(p3 >> 15) * 32 + j];                         \
        unsigned v4 = h32[(size_t)(p4 >> 15) * 32 + j];                         \
        unsigned v5 = h32[(size_t)(p5 >> 15) * 32 + j];                         \
        unsigned v6 = h32[(size_t)(p6 >> 15) * 32 + j];                         \
        unsigned v7 = h32[(size_t)(p7 >> 15) * 32 + j];                         \
        float w0 = __uint_as_float((p0 & 0x7FFFu) << 16);                       \
        float w1 = __uint_as_float((p1 & 0x7FFFu) << 16);                       \
        float w2 = __uint_as_float((p2 & 0x7FFFu) << 16);                       \
        float w3 = __uint_as_float((p3 & 0x7FFFu) << 16);                       \
        float w4 = __uint_as_float((p4 & 0x7FFFu) << 16);                       \
        float w5 = __uint_as_float((p5 & 0x7FFFu) << 16);                       \
        float w6 = __uint_as_float((p6 & 0x7FFFu) << 16);                       \
        float w7 = __uint_as_float((p7 & 0x7FFFu) << 16);                       \
        A0A = fmaf(__uint_as_float(v0 << 16), w0, A0A);                         \
        A0B = fmaf(__uint_as_float(v0 & 0xFFFF0000u), w0, A0B);                 \
        A1A = fmaf(__uint_as_float(v1 << 16), w1, A1A);                         \
        A1B = fmaf(__uint_as_float(v1 & 0xFFFF0000u), w1, A1B);                 \
        A2A = fmaf(__uint_as_float(v2 << 16), w2, A2A);                         \
        A2B = fmaf(__uint_as_float(v2 & 0xFFFF0000u), w2, A2B);                 \
        A3A = fmaf(__uint_as_float(v3 << 16), w3, A3A);                         \
        A3B = fmaf(__uint_as_float(v3 & 0xFFFF0000u), w3, A3B);                 \
        A0A = fmaf(__uint_as_float(v4 << 16), w4, A0A);                         \
        A0B = fmaf(__uint_as_float(v4 & 0xFFFF0000u), w4, A0B);                 \
        A1A = fmaf(__uint_as_float(v5 << 16), w5, A1A);                         \
        A1B = fmaf(__uint_as_float(v5 & 0xFFFF0000u), w5, A1B);                 \
        A2A = fmaf(__uint_as_float(v6 << 16), w6, A2A);                         \
        A2B = fmaf(__uint_as_float(v6 & 0xFFFF0000u), w6, A2B);                 \
        A3A = fmaf(__uint_as_float(v7 << 16), w7, A3A);                         \
        A3B = fmaf(__uint_as_float(v7 & 0xFFFF0000u), w7, A3B);                 \
    }

__global__ __launch_bounds__(256) void bgather_kernel(const __bf16* __restrict__ h,
                                                      const unsigned* __restrict__ payload2,
                                                      const int* __restrict__ noff,
                                                      float* __restrict__ out, int N) {
    const int t = threadIdx.x;
    const int hw = t >> 5;
    const int j = t & 31;
    const unsigned* __restrict__ h32 = (const unsigned*)h;
    const int g0 = blockIdx.x * 32;

#pragma unroll 1
    for (int k = 0; k < 4; ++k) {
        const int g = g0 + hw + k * 8;
        if (g >= N) continue;
        int i = noff[g];
        const int eE = noff[g + 1];
        float a0A = 0.f, a0B = 0.f, a1A = 0.f, a1B = 0.f;
        float a2A = 0.f, a2B = 0.f, a3A = 0.f, a3B = 0.f;
        float b0A = 0.f, b0B = 0.f, b1A = 0.f, b1B = 0.f;
        float b2A = 0.f, b2B = 0.f, b3A = 0.f, b3B = 0.f;
#pragma unroll 1
        for (; i + 16 <= eE; i += 16) {
            EDGE8P(payload2 + i, a0A, a0B, a1A, a1B, a2A, a2B, a3A, a3B)
            EDGE8P(payload2 + i + 8, b0A, b0B, b1A, b1B, b2A, b2B, b3A, b3B)
        }
        if (i + 8 <= eE) {
            EDGE8P(payload2 + i, a0A, a0B, a1A, a1B, a2A, a2B, a3A, a3B)
            i += 8;
        }
        for (; i + 2 <= eE; i += 2) {
            unsigned p0 = payload2[i + 0];
            unsigned p1 = payload2[i + 1];
            unsigned v0 = h32[(size_t)(p0 >> 15) * 32 + j];
            unsigned v1 = h32[(size_t)(p1 >> 15) * 32 + j];
            float w0 = __uint_as_float((p0 & 0x7FFFu) << 16);
            float w1 = __uint_as_float((p1 & 0x7FFFu) << 16);
            a0A = fmaf(__uint_as_float(v0 << 16), w0, a0A);
            a0B = fmaf(__uint_as_float(v0 & 0xFFFF0000u), w0, a0B);
            a1A = fmaf(__uint_as_float(v1 << 16), w1, a1A);
            a1B = fmaf(__uint_as_float(v1 & 0xFFFF0000u), w1, a1B);
        }
        if (i < eE) {
            unsigned p0 = payload2[i];
            unsigned v0 = h32[(size_t)(p0 >> 15) * 32 + j];
            float w0 = __uint_as_float((p0 & 0x7FFFu) << 16);
            a0A = fmaf(__uint_as_float(v0 << 16), w0, a0A);
            a0B = fmaf(__uint_as_float(v0 & 0xFFFF0000u), w0, a0B);
        }
        float2 v;
        v.x = fmaxf(((a0A + a1A) + (a2A + a3A)) + ((b0A + b1A) + (b2A + b3A)), 0.f);
        v.y = fmaxf(((a0B + a1B) + (a2B + a3B)) + ((b0B + b1B) + (b2B + b3B)), 0.f);
        *(float2*)(out + (size_t)g * OUT_F + 2 * j) = v;
    }
}

// ---------------------------------------------------------------- launch
extern "C" void kernel_launch(void* const* d_in, const int* in_sizes, int n_in,
                              void* d_out, int out_size, void* d_ws, size_t ws_size,
                              hipStream_t stream) {
    const float* feat = (const float*)d_in[0];
    const float* W    = (const float*)d_in[1];
    const float* ew   = (const float*)d_in[2];
    const int*   src  = (const int*)d_in[3];
    const int*   dst  = (const int*)d_in[4];
    float* out = (float*)d_out;

    const int N = in_sizes[0] / IN_F;
    const int E = in_sizes[2];
    const int nsb = (N + SBNODES - 1) >> LOGSB;

    char* ws = (char*)d_ws;
    int2*     payload  = (int2*)ws;     ws += (size_t)E * 8;          // 12.8 MB
    unsigned* payload2 = (unsigned*)ws; ws += (size_t)E * 4;          //  6.4 MB
    __bf16*   h        = (__bf16*)ws;   ws += (size_t)N * OUT_F * 2;  // 12.8 MB
    __bf16*   wfrag    = (__bf16*)ws;   ws += 32 * 64 * 8 * 2;        // 32 KB
    int*      bcnt     = (int*)ws;      ws += (MAXSB + 1) * 4;
    int*      sbcur    = (int*)ws;      ws += MAXSB * 4;
    int*      noff     = (int*)ws;                                    // (N+1)*4

    const int gemmBlocks = (N + 63) / 64;

    hipLaunchKernelGGL(wfrag_kernel, dim3(32), dim3(64), 0, stream, W, wfrag, bcnt, sbcur, nsb);
    hipLaunchKernelGGL(gemmhist_kernel, dim3(gemmBlocks + 512), dim3(256), 0, stream,
                       feat, wfrag, h, N, dst, bcnt, E, nsb, gemmBlocks);
    hipLaunchKernelGGL(sbscatter_kernel, dim3((E + 8191) / 8192), dim3(1024), 0, stream,
                       src, dst, ew, bcnt, sbcur, payload, E, nsb);
    hipLaunchKernelGGL(fsort_kernel, dim3(nsb), dim3(256), 0, stream,
                       payload, payload2, bcnt, noff, N, E, nsb);
    hipLaunchKernelGGL(bgather_kernel, dim3((N + 31) / 32), dim3(256), 0, stream,
                       h, payload2, noff, out, N);
}